// Round 5
// baseline (292.944 us; speedup 1.0000x reference)
//
#include <hip/hip_runtime.h>
#include <math.h>

#define NB 8
#define CC 14
#define HH 512
#define WW 512
#define HW (HH*WW)          // 262144
#define NHW (NB*HW)         // 2097152
#define WPR 8               // uint64 words per row (512 bits)
#define WPI (HH*WPR)        // 4096 words per image
#define KSPLIT 32
#define KCHUNK (HW/KSPLIT)  // 8192

typedef unsigned long long u64;

// ---- Stage A+B fused: argmax-gray tile in LDS + Sobel(replicate) + NMS ----
// R5: k_argmax removed; each block computes its own 68x68 gray tile directly
// from T (identical clamped-pixel argmax -> identical bytes), saving one
// dispatch boundary + the 4 MB tmap roundtrip. Halo re-reads (13%) are
// L2/L3-absorbed (inputs are restore-warmed in L3 per R2's FETCH evidence).
__global__ __launch_bounds__(256) void k_front(const float* __restrict__ T,
                                               u64* __restrict__ weakBits,
                                               u64* __restrict__ strongBits) {
    int tx = blockIdx.x, ty = blockIdx.y, n = blockIdx.z;
    int x0 = tx * 64, y0 = ty * 64;
    __shared__ unsigned char tm[68 * 68];
    __shared__ unsigned short ms[66 * 66];
    int tid = threadIdx.x;
    const float* Tb = T + (size_t)n * CC * HW;

    // phase 1: argmax over channels at replicate-clamped coords -> gray tile
    for (int idx = tid; idx < 68 * 68; idx += 256) {
        int r = idx / 68, c = idx - r * 68;
        int yy = y0 - 2 + r; yy = yy < 0 ? 0 : (yy > HH - 1 ? HH - 1 : yy);
        int xx = x0 - 2 + c; xx = xx < 0 ? 0 : (xx > WW - 1 ? WW - 1 : xx);
        const float* p = Tb + yy * WW + xx;
        float best = p[0];
        int bi = 0;
#pragma unroll
        for (int ch = 1; ch < CC; ++ch) {
            float v = p[(size_t)ch * HW];
            if (v > best) { best = v; bi = ch; }     // strict > = first-max (jnp.argmax)
        }
        // integer form of trunc((bi/13.0f)*255.0f): verified equal for bi in [0,13]
        tm[idx] = (unsigned char)((bi * 255) / 13);
    }
    __syncthreads();

    // phase 2: sobel -> (mag<<2)|sector for 66x66 (halo 1 for NMS)
    for (int idx = tid; idx < 66 * 66; idx += 256) {
        int r = idx / 66, c = idx - r * 66;
        const unsigned char* t0 = tm + r * 68 + c;   // top-left of 3x3
        int a00 = t0[0],   a01 = t0[1],   a02 = t0[2];
        int a10 = t0[68],                 a12 = t0[70];
        int a20 = t0[136], a21 = t0[137], a22 = t0[138];
        int gx = (a02 - a00) + 2 * (a12 - a10) + (a22 - a20);
        int gy = (a20 - a00) + 2 * (a21 - a01) + (a22 - a02);
        int m = (gx < 0 ? -gx : gx) + (gy < 0 ? -gy : gy);   // L1 magnitude, exact int
        float ang = atan2f((float)gy, (float)gx) * 57.29577951308232f;
        ang = fmodf(ang, 180.0f);
        if (ang < 0.0f) ang += 180.0f;
        int s;
        if (ang < 22.5f || ang >= 157.5f) s = 0;
        else if (ang < 67.5f)             s = 1;
        else if (ang < 112.5f)            s = 2;
        else                              s = 3;
        ms[idx] = (unsigned short)((m << 2) | s);
    }
    __syncthreads();

    // phase 3: NMS + ballot-pack; lane = x-in-tile (tile is one 64-bit word col)
    int lane = tid & 63;
    int warp = tid >> 6;
#pragma unroll
    for (int it = 0; it < 16; ++it) {
        int row = it * 4 + warp;
        int gy_ = y0 + row, gx_ = x0 + lane;
        int v = ms[(row + 1) * 66 + (lane + 1)];
        int mc = v >> 2, s = v & 3;
        int dy1, dx1, dy2, dx2;
        if (s == 0)      { dy1 = 0;  dx1 = 1;  dy2 = 0; dx2 = -1; }
        else if (s == 1) { dy1 = -1; dx1 = 1;  dy2 = 1; dx2 = -1; }
        else if (s == 2) { dy1 = -1; dx1 = 0;  dy2 = 1; dx2 = 0;  }
        else             { dy1 = -1; dx1 = -1; dy2 = 1; dx2 = 1;  }
        int y1 = gy_ + dy1, x1 = gx_ + dx1, y2 = gy_ + dy2, x2 = gx_ + dx2;
        int n1 = (y1 < 0 || y1 >= HH || x1 < 0 || x1 >= WW)
                 ? 0 : (ms[(row + 1 + dy1) * 66 + (lane + 1 + dx1)] >> 2);
        int n2 = (y2 < 0 || y2 >= HH || x2 < 0 || x2 >= WW)
                 ? 0 : (ms[(row + 1 + dy2) * 66 + (lane + 1 + dx2)] >> 2);
        int nms = (mc >= n1 && mc >= n2) ? mc : 0;
        u64 wm = __ballot(nms > 10);
        u64 sm = __ballot(nms > 50);
        if (lane == 0) {
            size_t w = (size_t)n * WPI + gy_ * WPR + tx;
            weakBits[w]   = wm;
            strongBits[w] = sm;
        }
    }
}

// ---- Stage C+D+E: 16 hysteresis iters + 10x10 dilate + 10x10 blur, fused --
// R5: exact-fit 576 threads (TWORDS=576 at HALO=28) -> grow iteration is
// exactly one word per thread (no ragged 2nd pass on the 16x critical path);
// weak word register-cached; Wl LDS buffer dropped (A reused as D).
// Exactness (HALO=28 >= 26): A exact on local rows [16, 55]; D row d needs
// h-dilated B rows [d+18, d+27] for d in [0,25] -> [18,52] subset of [16,55].
#define TR 16
#define HALO 28
#define TROWS (TR + 2*HALO)    // 72
#define TWORDS (TROWS * WPR)   // 576
#define DROWS (TR + 10)        // 26
#define HYST_THREADS 576
__global__ __launch_bounds__(HYST_THREADS) void k_hyst_dil_blur(const u64* __restrict__ strongBits,
                                                                const u64* __restrict__ weakBits,
                                                                unsigned char* __restrict__ E) {
    int tile = blockIdx.x & 31;
    int n    = blockIdx.x >> 5;
    int t0r  = tile * TR;
    int g0   = t0r - HALO;                 // virtual first row of tile
    __shared__ u64 A[TWORDS];
    __shared__ u64 B[TWORDS];
    __shared__ unsigned char rc[DROWS * 512]; // horizontal blur rowcounts
    int tid = threadIdx.x;                 // 0..575, exactly one word/thread
    int r = tid >> 3;                      // local row 0..71
    int w = tid & 7;                       // word-in-row

    int vr = g0 + r;
    u64 sv = 0, wk = 0;
    if (vr >= 0 && vr < HH) {
        sv = strongBits[(size_t)n * WPI + vr * WPR + w];
        wk = weakBits  [(size_t)n * WPI + vr * WPR + w];
    }
    A[tid] = sv;
    __syncthreads();

#pragma unroll 1
    for (int it = 0; it < 16; ++it) {
        const u64* src = (it & 1) ? B : A;
        u64*       dst = (it & 1) ? A : B;
        u64 c  = src[tid];
        u64 up = (r > 0)         ? src[tid - 8] : 0;
        u64 dn = (r < TROWS - 1) ? src[tid + 8] : 0;
        u64 a = c | up | dn;
        u64 pL = 0, pR = 0;
        if (w > 0) {
            u64 cl = src[tid - 1];
            u64 ul = (r > 0)         ? src[tid - 9] : 0;
            u64 dl = (r < TROWS - 1) ? src[tid + 7] : 0;
            pL = cl | ul | dl;
        }
        if (w < 7) {
            u64 cr = src[tid + 1];
            u64 ur = (r > 0)         ? src[tid - 7] : 0;
            u64 dr = (r < TROWS - 1) ? src[tid + 9] : 0;
            pR = cr | ur | dr;
        }
        u64 g = a | (a << 1) | (pL >> 63) | (a >> 1) | (pR << 63);
        __syncthreads();                   // all reads of src done before dst write
        dst[tid] = g & wk;
        __syncthreads();
    }
    // result (after 16 iters) is in A

    // dilate horizontal: window [x-5, x+4]; read A -> write B
    {
        u64 v  = A[tid];
        u64 p  = (w > 0) ? A[tid - 1] : 0;
        u64 nx = (w < 7) ? A[tid + 1] : 0;
        u64 o = v;
#pragma unroll
        for (int d = 1; d <= 5; ++d) o |= (v << d) | (p >> (64 - d));
#pragma unroll
        for (int d = 1; d <= 4; ++d) o |= (v >> d) | (nx << (64 - d));
        __syncthreads();
        B[tid] = o;
    }
    __syncthreads();

    // dilate vertical: window [y-5, y+4]; read B -> write D (= A, dead now).
    // D row d (d in [0,DROWS)) = dil at global row t0r-5+d, local d+HALO-5.
    u64* D = A;
    if (tid < DROWS * WPR) {
        int d  = tid >> 3;
        int rr = d + HALO - 5;
        u64 o = 0;
#pragma unroll
        for (int dy = -5; dy <= 4; ++dy) o |= B[(rr + dy) * WPR + w];
        D[d * WPR + w] = o;
    }
    __syncthreads();

    // horizontal 10-bit window popcount per pixel (reflect101 at x edges)
    for (int idx = tid; idx < DROWS * 512; idx += HYST_THREADS) {
        int rr = idx >> 9;
        int x  = idx & 511;
        int c;
        if (x >= 5 && x <= 507) {
            int b = x - 5, wd = b >> 6, off = b & 63;
            u64 v = D[rr * WPR + wd] >> off;
            if (off && wd < 7) v |= D[rr * WPR + wd + 1] << (64 - off);
            c = __popcll(v & 0x3FFull);
        } else {
            c = 0;
            for (int dx = -5; dx <= 4; ++dx) {
                int xx = x + dx;
                xx = xx < 0 ? -xx : (xx > WW - 1 ? 2 * (WW - 1) - xx : xx);
                c += (int)((D[rr * WPR + (xx >> 6)] >> (xx & 63)) & 1ull);
            }
        }
        rc[idx] = (unsigned char)c;
    }
    __syncthreads();

    // vertical 10-row sum (reflect101 rows at image borders), quantize, store
    // E byte k: edge value = k/255 with k = rint(255*cnt/100) (exact int-val float)
    for (int idx = tid; idx < TR * 512; idx += HYST_THREADS) {
        int yy = idx >> 9;
        int x  = idx & 511;
        int gy = t0r + yy;
        int sum = 0;
        if (gy >= 5 && gy <= HH - 5) {          // window fully inside image
#pragma unroll
            for (int k = 0; k < 10; ++k) sum += rc[(yy + k) * 512 + x];
        } else {
#pragma unroll
            for (int k = 0; k < 10; ++k) {
                int v  = gy - 5 + k;
                int rv = v < 0 ? -v : (v > HH - 1 ? 2 * (HH - 1) - v : v);
                sum += rc[(rv - (t0r - 5)) * 512 + x];
            }
        }
        float b = rintf((255.0f * (float)sum) / 100.0f);   // round half to even
        E[(size_t)n * HW + gy * WW + x] = (unsigned char)b;
    }
}

// ---- Stage F: per-(n,c) KL partials — no max shift needed -----------------
// |e*pred| <= ~6 so exp() never overflows; Z <= ~5e7 fits float easily.
// loss_nc = Wt/Zt - log Zt + log Zs with Zt=sum e^t, Wt=sum e^t (t-s), Zs=sum e^s
// Element->thread mapping and per-thread f32 accumulation order are FROZEN
// (bit-exact vs reference across 4 rounds; do not regroup).
// NOTE: NO device-scope fence/atomic finalize here — costs ~185 us.
__global__ __launch_bounds__(256) void k_kl_partial(const float* __restrict__ S,
                                                    const float* __restrict__ T,
                                                    const unsigned char* __restrict__ E,
                                                    double* __restrict__ partial) {
    int cidx  = blockIdx.x;   // n*CC + c
    int split = blockIdx.y;   // 0..KSPLIT-1
    int n = cidx / CC;
    const float4* Tp = (const float4*)(T + (size_t)cidx * HW + (size_t)split * KCHUNK);
    const float4* Sp = (const float4*)(S + (size_t)cidx * HW + (size_t)split * KCHUNK);
    const uchar4* Ep = (const uchar4*)(E + (size_t)n    * HW + (size_t)split * KCHUNK);
    int tid = threadIdx.x;

    __shared__ float lut[256];
    lut[tid] = (float)tid / 255.0f;       // IEEE div, same value as inline path
    __syncthreads();

    float Zt = 0.0f, Wt = 0.0f, Zs = 0.0f;
#pragma unroll
    for (int k = 0; k < KCHUNK / 4 / 256; ++k) {       // 8 iterations
        int j = k * 256 + tid;
        float4 t4 = Tp[j];
        float4 s4 = Sp[j];
        uchar4 e4 = Ep[j];
#pragma unroll
        for (int u = 0; u < 4; ++u) {
            float e = lut[(&e4.x)[u]];
            float t = e * (&t4.x)[u];
            float s = e * (&s4.x)[u];
            float et = __expf(t);
            Zt += et;
            Wt += et * (t - s);
            Zs += __expf(s);
        }
    }

    // wave-level shuffle reduction (double), then 4-wave LDS combine
    double zt = (double)Zt, wt = (double)Wt, zs = (double)Zs;
#pragma unroll
    for (int off = 32; off > 0; off >>= 1) {
        zt += __shfl_down(zt, off);
        wt += __shfl_down(wt, off);
        zs += __shfl_down(zs, off);
    }
    __shared__ double wr[4][3];
    int wv = tid >> 6, ln = tid & 63;
    if (ln == 0) { wr[wv][0] = zt; wr[wv][1] = wt; wr[wv][2] = zs; }
    __syncthreads();
    if (tid == 0) {
        double* o = partial + ((size_t)cidx * KSPLIT + split) * 3;
        o[0] = wr[0][0] + wr[1][0] + wr[2][0] + wr[3][0];
        o[1] = wr[0][1] + wr[1][1] + wr[2][1] + wr[3][1];
        o[2] = wr[0][2] + wr[1][2] + wr[2][2] + wr[3][2];
    }
}

// ---- Stage G: final reduce -> scalar loss ---------------------------------
__global__ __launch_bounds__(128) void k_kl_final(const double* __restrict__ partial,
                                                  float* __restrict__ out) {
    int tid = threadIdx.x;
    double loss = 0.0;
    if (tid < NB * CC) {
        double Zt = 0.0, Wt = 0.0, Zs = 0.0;
        for (int sp = 0; sp < KSPLIT; ++sp) {
            const double* p = partial + ((size_t)tid * KSPLIT + sp) * 3;
            Zt += p[0]; Wt += p[1]; Zs += p[2];
        }
        loss = Wt / Zt - log(Zt) + log(Zs);
    }
    __shared__ double red[128];
    red[tid] = loss;
    __syncthreads();
    for (int off = 64; off > 0; off >>= 1) {
        if (tid < off) red[tid] += red[tid + off];
        __syncthreads();
    }
    if (tid == 0) out[0] = (float)(red[0] / (double)(NB * CC));  // T^2 = 1
}

extern "C" void kernel_launch(void* const* d_in, const int* in_sizes, int n_in,
                              void* d_out, int out_size, void* d_ws, size_t ws_size,
                              hipStream_t stream) {
    const float* S = (const float*)d_in[0];   // preds_S
    const float* T = (const float*)d_in[1];   // preds_T
    float* out = (float*)d_out;

    char* ws = (char*)d_ws;
    unsigned char* e_buf      = (unsigned char*)(ws);                        // 2 MB (uint8)
    u64*           weakBits   = (u64*)(ws + (size_t)NHW);                    // 256 KB
    u64*           strongBits = (u64*)(ws + (size_t)NHW + (NHW/8));          // 256 KB
    double*        partial    = (double*)(ws + (size_t)NHW + 2*(NHW/8));     // 86 KB

    k_front<<<dim3(8, 8, NB), dim3(256), 0, stream>>>(T, weakBits, strongBits);
    k_hyst_dil_blur<<<dim3(NB * 32), dim3(HYST_THREADS), 0, stream>>>(strongBits, weakBits, e_buf);
    k_kl_partial<<<dim3(NB * CC, KSPLIT), dim3(256), 0, stream>>>(S, T, e_buf, partial);
    k_kl_final<<<1, 128, 0, stream>>>(partial, out);
    (void)in_sizes; (void)n_in; (void)out_size; (void)ws_size;
}